// Round 8
// baseline (1266.841 us; speedup 1.0000x reference)
//
#include <hip/hip_runtime.h>
#include <hip/hip_bf16.h>

typedef __bf16 bf16;
typedef bf16 bf16x8 __attribute__((ext_vector_type(8)));
typedef bf16 bf16x4 __attribute__((ext_vector_type(4)));
typedef float f32x4 __attribute__((ext_vector_type(4)));
typedef unsigned int u32;
typedef unsigned short u16;

#define Bsz 512
#define Ssz 199
#define Dsz 128
#define GR 16
#define NBLK (Bsz / GR)
#define BTot (Bsz * Ssz)

__device__ __forceinline__ float fsig(float x) {
  return __builtin_amdgcn_rcpf(1.f + __builtin_amdgcn_exp2f(x * -1.44269504f));
}
__device__ __forceinline__ float ftanh(float x) {
  return 1.f - 2.f * __builtin_amdgcn_rcpf(1.f + __builtin_amdgcn_exp2f(x * 2.88539008f));
}
__device__ __forceinline__ f32x4 mfma16(bf16x8 a, bf16x8 b, f32x4 c) {
  return __builtin_amdgcn_mfma_f32_16x16x32_bf16(a, b, c, 0, 0, 0);
}
__device__ __forceinline__ bf16x8 ldfrag(const bf16* PW, int KS, int nt, int ks, int lane) {
  return *(const bf16x8*)&PW[(size_t)((nt * KS + ks) * 64 + lane) * 8];
}
__device__ __forceinline__ void keep(bf16x8& v) {
  f32x4& f = reinterpret_cast<f32x4&>(v);
  asm volatile("" : "+v"(f));
}
// raw barrier: orders LDS only; global ops stay in flight
__device__ __forceinline__ void barRaw() {
  __builtin_amdgcn_sched_barrier(0);
  asm volatile("s_waitcnt lgkmcnt(0)" ::: "memory");
  __builtin_amdgcn_s_barrier();
  __builtin_amdgcn_sched_barrier(0);
}
// draining barrier: makes this step's stores visible to next step's loads
__device__ __forceinline__ void barVm() {
  __builtin_amdgcn_sched_barrier(0);
  asm volatile("s_waitcnt vmcnt(0) lgkmcnt(0)" ::: "memory");
  __builtin_amdgcn_s_barrier();
  __builtin_amdgcn_sched_barrier(0);
}

// ---------------- K1: packed per-(b,t) index stream: lpt | lst<<8 ----------------
__global__ void k_idx(const int* __restrict__ np_, const int* __restrict__ ns_,
                      u32* __restrict__ idx) {
  __shared__ u16 tabP[20000];
  __shared__ u16 tabS[500];
  __shared__ u16 pb[Ssz], sb[Ssz];
  int b = blockIdx.x;
  for (int i = threadIdx.x; i < 20000; i += blockDim.x) tabP[i] = 0;
  for (int i = threadIdx.x; i < 500; i += blockDim.x) tabS[i] = 0;
  for (int i = threadIdx.x; i < Ssz; i += blockDim.x) {
    pb[i] = (u16)np_[b * Ssz + i];
    sb[i] = (u16)ns_[b * Ssz + i];
  }
  __syncthreads();
  if (threadIdx.x == 0) {
    for (int t = 0; t < Ssz; ++t) {
      int p = pb[t], s = sb[t];
      idx[b * Ssz + t] = (u32)tabP[p] | ((u32)tabS[s] << 8);
      tabP[p] = (u16)t;
      tabS[s] = (u16)t;
    }
  }
}

// ---------------- K2: pack weights into MFMA B-fragment layout ----------------
__global__ void k_pack(const float* __restrict__ W, bf16* __restrict__ dst, int K) {
  int g = blockIdx.x * blockDim.x + threadIdx.x;
  int KS = K / 32;
  int total = 8 * KS * 64;
  if (g >= total) return;
  int l = g & 63;
  int ks = (g >> 6) % KS;
  int nt = (g >> 6) / KS;
  int col = nt * 16 + (l & 15);
  int k0 = ks * 32 + (l >> 4) * 8;
  bf16x8 v;
  for (int j = 0; j < 8; ++j) v[j] = (bf16)W[(size_t)(k0 + j) * 128 + col];
  *(bf16x8*)&dst[(size_t)g * 8] = v;
}

// ---------------- K3: time-embedding projections (bias folded) ----------------
__global__ void k_tge(const float* __restrict__ TE, const float* __restrict__ W,
                      const float* __restrict__ bias, float* __restrict__ dst) {
  __shared__ float te[128];
  int d = blockIdx.x, n = threadIdx.x;
  te[n] = TE[d * 128 + n];
  __syncthreads();
  float acc = bias[n];
  for (int k = 0; k < 128; ++k) acc += te[k] * W[(size_t)(128 + k) * 128 + n];
  dst[d * 128 + n] = acc;
}

// ---------------- K4: nX stream, [t][B][128] bf16 ----------------
__global__ void k_embed(const int* __restrict__ np_, const int* __restrict__ ns_,
                        const int* __restrict__ na_,
                        const float* __restrict__ pe, const float* __restrict__ se,
                        const float* __restrict__ diff, const float* __restrict__ chg,
                        const float* __restrict__ ae, bf16* __restrict__ nXsS) {
  int g = blockIdx.x * 256 + threadIdx.x;
  int bt = g >> 5, cg = (g & 31) * 4;
  if (bt >= BTot) return;
  int b = bt / Ssz, t = bt - b * Ssz;
  int p = np_[bt], s = ns_[bt], a = na_[bt];
  float d = diff[p];
  f32x4 vp = *(const f32x4*)&pe[(size_t)p * 128 + cg];
  f32x4 vs = *(const f32x4*)&se[(size_t)s * 128 + cg];
  f32x4 vc = *(const f32x4*)&chg[(size_t)s * 128 + cg];
  f32x4 va = *(const f32x4*)&ae[(size_t)a * 128 + cg];
  bf16x4 ox;
  for (int j = 0; j < 4; ++j) ox[j] = (bf16)(vp[j] + vs[j] + d * vc[j] + va[j]);
  *(bf16x4*)&nXsS[((size_t)t * Bsz + b) * 128 + cg] = ox;
}

// ---------------- main recurrent kernel: 2 barriers/step, direct install ----------------
struct MainParams {
  const float *ls_state, *pro_state0, *skill_state0;
  const u32 *idx;
  const bf16 *nXsS;
  const float *TGEp, *TGEs, *cAF;
  const bf16 *PWpf, *PWsf, *PWaf, *PWps, *PWss, *PWas;
  const float *b_ps, *b_ss, *b_as;
  bf16 *proSt, *skSt, *Sla, *Slbp, *Slbs;
};

__global__ void __launch_bounds__(512) k_main(MainParams P) {
  const int b0 = blockIdx.x * GR;
  const int tid = threadIdx.x;
  const int lane = tid & 63;
  const int wv = tid >> 6;        // wave owns output cols [wv*16, wv*16+16)
  const int r32 = tid >> 5;       // c4-mapping row (vector ops)
  const int c4 = (tid & 31) * 4;  // c4-mapping col group
  const int arow = lane & 15, apos = (lane >> 4) * 8;
  const int rb = (lane >> 4) * 4;          // cA-mapping rows rb..rb+3
  const int cA = wv * 16 + (lane & 15);    // cA-mapping col

  __shared__ __align__(16) bf16 Ala[16][132], Albp[16][132], Albs[16][132];
  __shared__ __align__(16) bf16 AnX[2][16][132];
  __shared__ __align__(16) bf16 AlaG[16][132], AlbpG[16][132], AlbsG[16][132];
  __shared__ __align__(16) bf16 STG0[2][16][132], STG1[2][16][132];
  __shared__ u32 idxL[GR * Ssz];

  // ---- register-resident weight slices ----
  bf16x8 Gpf[4], Gsf[4], Gaf[4], Wps[8], Wss[8], Was[8];
#pragma unroll
  for (int ks = 0; ks < 4; ++ks) {
    Gpf[ks] = ldfrag(P.PWpf, 4, wv, ks, lane);
    Gsf[ks] = ldfrag(P.PWsf, 4, wv, ks, lane);
    Gaf[ks] = ldfrag(P.PWaf, 4, wv, ks, lane);
  }
#pragma unroll
  for (int ks = 0; ks < 8; ++ks) {
    Wps[ks] = ldfrag(P.PWps, 8, wv, ks, lane);
    Wss[ks] = ldfrag(P.PWss, 8, wv, ks, lane);
    Was[ks] = ldfrag(P.PWas, 8, wv, ks, lane);
  }
#pragma unroll
  for (int ks = 0; ks < 4; ++ks) {
    keep(Gpf[ks]);
    keep(Gsf[ks]);
    keep(Gaf[ks]);
  }
#pragma unroll
  for (int ks = 0; ks < 8; ++ks) {
    keep(Wps[ks]);
    keep(Wss[ks]);
    keep(Was[ks]);
  }
  const float bpsv = P.b_ps[cA], bssv = P.b_ss[cA], basv = P.b_as[cA], cafv = P.cAF[cA];

  for (int i = tid; i < GR * Ssz; i += 512) idxL[i] = P.idx[b0 * Ssz + i];

  // ---- t=0 installs (c4 mapping) ----
  float gpcP[4], gpcS[4];
  {
    bf16x4 va, vp, vs;
    for (int j = 0; j < 4; ++j) {
      va[j] = (bf16)P.ls_state[c4 + j];
      vp[j] = (bf16)P.pro_state0[c4 + j];
      vs[j] = (bf16)P.skill_state0[c4 + j];
    }
    *(bf16x4*)&Ala[r32][c4] = va;
    *(bf16x4*)&Albp[r32][c4] = vp;
    *(bf16x4*)&Albs[r32][c4] = vs;
    *(bf16x4*)&AnX[0][r32][c4] = *(const bf16x4*)&P.nXsS[(size_t)(b0 + r32) * Dsz + c4];
#pragma unroll
    for (int r = 0; r < 4; ++r) {
      gpcP[r] = P.TGEp[cA];  // t=0: lpt=lst=0 -> TGE row 0
      gpcS[r] = P.TGEs[cA];
    }
  }
  __syncthreads();

  for (int t = 0; t < Ssz; ++t) {
    const bool pf = (t + 1 < Ssz);
    const int cur = t & 1, prv = cur ^ 1;
    // ==== PHASE 1 ====
    // store t-1 states (c4, from STG[prv]); full step of drain cover until barVm
    if (t > 0) {
      size_t sb = ((size_t)(b0 + r32) * Ssz + (t - 1)) * Dsz + c4;
      *(bf16x4*)&P.proSt[sb] = *(const bf16x4*)&STG0[prv][r32][c4];
      *(bf16x4*)&P.skSt[sb] = *(const bf16x4*)&STG1[prv][r32][c4];
    }
    // prefetch t+1 operands in the cA mapping (consumed at E, same-thread)
    int lpN[4], lsN[4];
    float gpnP[4], gpnS[4];
    bf16 pPro[4], pSk[4], pNxs[4];
    if (pf) {
#pragma unroll
      for (int r = 0; r < 4; ++r) {
        u32 iw = idxL[(rb + r) * Ssz + t + 1];
        lpN[r] = iw & 255;
        lsN[r] = (iw >> 8) & 255;
        gpnP[r] = P.TGEp[(size_t)(t + 1 - lpN[r]) * Dsz + cA];
        gpnS[r] = P.TGEs[(size_t)(t + 1 - lsN[r]) * Dsz + cA];
        pPro[r] = (bf16)0.f;
        pSk[r] = (bf16)0.f;
        if (lpN[r] < t - 1)
          pPro[r] = P.proSt[((size_t)(b0 + rb + r) * Ssz + lpN[r]) * Dsz + cA];
        if (lsN[r] < t - 1)
          pSk[r] = P.skSt[((size_t)(b0 + rb + r) * Ssz + lsN[r]) * Dsz + cA];
        pNxs[r] = P.nXsS[((size_t)(t + 1) * Bsz + (b0 + rb + r)) * Dsz + cA];
      }
    }
    // B: gate matmuls (K=128), gate bias pre-loaded into accumulators
    f32x4 dpf = {gpcP[0], gpcP[1], gpcP[2], gpcP[3]};
    f32x4 dsf = {gpcS[0], gpcS[1], gpcS[2], gpcS[3]};
    f32x4 daf = {cafv, cafv, cafv, cafv};
#pragma unroll
    for (int ks = 0; ks < 4; ++ks) {
      bf16x8 ap = *(const bf16x8*)&Albp[arow][ks * 32 + apos];
      bf16x8 av = *(const bf16x8*)&Albs[arow][ks * 32 + apos];
      bf16x8 aa = *(const bf16x8*)&Ala[arow][ks * 32 + apos];
      dpf = mfma16(ap, Gpf[ks], dpf);
      dsf = mfma16(av, Gsf[ks], dsf);
      daf = mfma16(aa, Gaf[ks], daf);
    }
    // C: gate epilogue -> G-tiles (cA mapping)
    float gP[4], gS[4], gA[4];
#pragma unroll
    for (int r = 0; r < 4; ++r) {
      int row = rb + r;
      float gv = (float)Albp[row][cA] * fsig(dpf[r]);
      gP[r] = gv;
      AlbpG[row][cA] = (bf16)gv;
      float gw = (float)Albs[row][cA] * fsig(dsf[r]);
      gS[r] = gw;
      AlbsG[row][cA] = (bf16)gw;
      float gx = (float)Ala[row][cA] * fsig(daf[r]);
      gA[r] = gx;
      AlaG[row][cA] = (bf16)gx;
    }
    barRaw();  // barrier 1: G-tiles ready for D
    // ==== PHASE 2 ====
    // head-input dumps (c4, vector) from stable G-tiles
    {
      size_t db = ((size_t)(b0 + r32) * Ssz + t) * Dsz + c4;
      *(bf16x4*)&P.Sla[db] = *(const bf16x4*)&AlaG[r32][c4];
      *(bf16x4*)&P.Slbp[db] = *(const bf16x4*)&AlbpG[r32][c4];
      *(bf16x4*)&P.Slbs[db] = *(const bf16x4*)&AlbsG[r32][c4];
    }
    // D: update matmuls (K=256) on gated tiles + AnX[cur]
    f32x4 uas{}, ups{}, uss{};
#pragma unroll
    for (int ks = 0; ks < 4; ++ks) {
      bf16x8 aa = *(const bf16x8*)&AlaG[arow][ks * 32 + apos];
      bf16x8 ap = *(const bf16x8*)&AlbpG[arow][ks * 32 + apos];
      bf16x8 av = *(const bf16x8*)&AlbsG[arow][ks * 32 + apos];
      bf16x8 ax = *(const bf16x8*)&AnX[cur][arow][ks * 32 + apos];
      uas = mfma16(aa, Was[ks], uas);
      uas = mfma16(ax, Was[ks + 4], uas);
      ups = mfma16(ap, Wps[ks], ups);
      ups = mfma16(ax, Wps[ks + 4], ups);
      uss = mfma16(av, Wss[ks], uss);
      uss = mfma16(ax, Wss[ks + 4], uss);
    }
    // E: update epilogue + DIRECT install of t+1 operands (same thread, same (row,cA))
#pragma unroll
    for (int r = 0; r < 4; ++r) {
      int row = rb + r;
      bf16 bAll = (bf16)(gA[r] + ftanh(uas[r] + basv));
      bf16 bPro = (bf16)(gP[r] + ftanh(ups[r] + bpsv));
      bf16 bSk = (bf16)(gS[r] + ftanh(uss[r] + bssv));
      STG0[cur][row][cA] = bPro;
      STG1[cur][row][cA] = bSk;
      if (pf) {
        Ala[row][cA] = bAll;
        bf16 vp = (lpN[r] == t) ? bPro
                                : ((lpN[r] == t - 1) ? STG0[prv][row][cA] : pPro[r]);
        Albp[row][cA] = vp;
        bf16 vs = (lsN[r] == t) ? bSk
                                : ((lsN[r] == t - 1) ? STG1[prv][row][cA] : pSk[r]);
        Albs[row][cA] = vs;
        AnX[prv][row][cA] = pNxs[r];  // next step's cur == prv
        gpcP[r] = gpnP[r];
        gpcS[r] = gpnS[r];
      }
    }
    barVm();  // barrier 2: installs ordered; this step's stores made visible
  }
  // final state store (t = Ssz-1 results live in STG[(Ssz-1)&1])
  {
    const int last = (Ssz - 1) & 1;
    size_t sb = ((size_t)(b0 + r32) * Ssz + (Ssz - 1)) * Dsz + c4;
    *(bf16x4*)&P.proSt[sb] = *(const bf16x4*)&STG0[last][r32][c4];
    *(bf16x4*)&P.skSt[sb] = *(const bf16x4*)&STG1[last][r32][c4];
  }
}

// ---------------- deferred head: 32 rows/block ----------------
struct HeadParams {
  const bf16 *Sla, *Slbp, *Slbs, *PWo1;
  const int *next_problem, *next_skill;
  const float *pro_embed, *skill_embed, *akt_pro_diff, *akt_pro_change;
  const float *b_o1, *W_o2, *b_o2;
  float *out;
};

__global__ void k_head(HeadParams P) {
  const int bt0 = blockIdx.x * 32;
  const int tid = threadIdx.x, lane = tid & 63, wv = tid >> 6;
  const int r16 = tid >> 4, c8 = (tid & 15) * 8;
  const int arow = lane & 15, apos = (lane >> 4) * 8;
  const int rb = (lane >> 4) * 4;
  const int nt0 = wv, nt1 = wv + 4;
  const int cAh = nt0 * 16 + (lane & 15), cBh = nt1 * 16 + (lane & 15);
  __shared__ __align__(16) bf16 Af[32][520];
  __shared__ float Hh[32][132];
  __shared__ float Hpart[32][16];
  __shared__ float w2s[128];
  if (tid < 128) w2s[tid] = P.W_o2[tid];
  for (int half = 0; half < 2; ++half) {
    int row = half * 16 + r16;
    int bt = bt0 + row;
    *(bf16x8*)&Af[row][c8] = *(const bf16x8*)&P.Sla[(size_t)bt * 128 + c8];
    *(bf16x8*)&Af[row][128 + c8] = *(const bf16x8*)&P.Slbp[(size_t)bt * 128 + c8];
    *(bf16x8*)&Af[row][256 + c8] = *(const bf16x8*)&P.Slbs[(size_t)bt * 128 + c8];
    int np = P.next_problem[bt], ns = P.next_skill[bt];
    float diff = P.akt_pro_diff[np];
    f32x4 p0 = *(const f32x4*)&P.pro_embed[(size_t)np * 128 + c8];
    f32x4 p1 = *(const f32x4*)&P.pro_embed[(size_t)np * 128 + c8 + 4];
    f32x4 s0 = *(const f32x4*)&P.skill_embed[(size_t)ns * 128 + c8];
    f32x4 s1 = *(const f32x4*)&P.skill_embed[(size_t)ns * 128 + c8 + 4];
    f32x4 c0 = *(const f32x4*)&P.akt_pro_change[(size_t)ns * 128 + c8];
    f32x4 c1 = *(const f32x4*)&P.akt_pro_change[(size_t)ns * 128 + c8 + 4];
    bf16x8 vn;
    for (int j = 0; j < 4; ++j) {
      vn[j] = (bf16)(p0[j] + s0[j] + diff * c0[j]);
      vn[j + 4] = (bf16)(p1[j] + s1[j] + diff * c1[j]);
    }
    *(bf16x8*)&Af[row][384 + c8] = vn;
  }
  __syncthreads();
  f32x4 h0{}, h1{}, h2{}, h3{};
#pragma unroll
  for (int ks = 0; ks < 16; ++ks) {
    bf16x8 a0 = *(const bf16x8*)&Af[arow][ks * 32 + apos];
    bf16x8 a1 = *(const bf16x8*)&Af[16 + arow][ks * 32 + apos];
    bf16x8 bA = ldfrag(P.PWo1, 16, nt0, ks, lane);
    bf16x8 bB = ldfrag(P.PWo1, 16, nt1, ks, lane);
    h0 = mfma16(a0, bA, h0);
    h1 = mfma16(a0, bB, h1);
    h2 = mfma16(a1, bA, h2);
    h3 = mfma16(a1, bB, h3);
  }
  const float bo1A = P.b_o1[cAh], bo1B = P.b_o1[cBh];
  for (int r = 0; r < 4; ++r) {
    Hh[rb + r][cAh] = fmaxf(h0[r] + bo1A, 0.f);
    Hh[rb + r][cBh] = fmaxf(h1[r] + bo1B, 0.f);
    Hh[16 + rb + r][cAh] = fmaxf(h2[r] + bo1A, 0.f);
    Hh[16 + rb + r][cBh] = fmaxf(h3[r] + bo1B, 0.f);
  }
  __syncthreads();
  for (int half = 0; half < 2; ++half) {
    int row = half * 16 + (tid >> 4), cg = tid & 15;
    float s = 0.f;
#pragma unroll
    for (int j = 0; j < 8; ++j) s += Hh[row][cg * 8 + j] * w2s[cg * 8 + j];
    Hpart[row][cg] = s;
  }
  __syncthreads();
  if (tid < 32) {
    float s = 0.f;
#pragma unroll
    for (int k = 0; k < 16; ++k) s += Hpart[tid][k];
    P.out[bt0 + tid] = fsig(s + P.b_o2[0]);
  }
}

extern "C" void kernel_launch(void* const* d_in, const int* in_sizes, int n_in,
                              void* d_out, int out_size, void* d_ws, size_t ws_size,
                              hipStream_t stream) {
  const int* next_problem = (const int*)d_in[3];
  const int* next_skill = (const int*)d_in[4];
  const int* next_ans = (const int*)d_in[5];
  const float* pro_embed = (const float*)d_in[6];
  const float* skill_embed = (const float*)d_in[7];
  const float* ans_embed = (const float*)d_in[8];
  const float* time_embed = (const float*)d_in[9];
  const float* ls_state = (const float*)d_in[10];
  const float* pro_state0 = (const float*)d_in[11];
  const float* skill_state0 = (const float*)d_in[12];
  const float* akt_pro_diff = (const float*)d_in[13];
  const float* akt_pro_change = (const float*)d_in[14];
  const float* W_pf = (const float*)d_in[15];
  const float* b_pf = (const float*)d_in[16];
  const float* W_sf = (const float*)d_in[17];
  const float* b_sf = (const float*)d_in[18];
  const float* W_af = (const float*)d_in[19];
  const float* b_af = (const float*)d_in[20];
  const float* W_ps = (const float*)d_in[21];
  const float* b_ps = (const float*)d_in[22];
  const float* W_ss = (const float*)d_in[23];
  const float* b_ss = (const float*)d_in[24];
  const float* W_as = (const float*)d_in[25];
  const float* b_as = (const float*)d_in[26];
  const float* W_o1 = (const float*)d_in[27];
  const float* b_o1 = (const float*)d_in[28];
  const float* W_o2 = (const float*)d_in[29];
  const float* b_o2 = (const float*)d_in[30];

  char* ws = (char*)d_ws;
  size_t off = 0;
  auto alloc = [&](size_t bytes) -> void* {
    void* p = ws + off;
    off += bytes;
    off = (off + 255) & ~(size_t)255;
    return p;
  };
  bf16* proSt = (bf16*)alloc((size_t)Bsz * Ssz * Dsz * 2);
  bf16* skSt = (bf16*)alloc((size_t)Bsz * Ssz * Dsz * 2);
  u32* idx = (u32*)alloc((size_t)BTot * 4);
  float* TGEp = (float*)alloc(200 * 128 * 4);
  float* TGEs = (float*)alloc(200 * 128 * 4);
  float* cAF = (float*)alloc(128 * 4);
  bf16* PWpf = (bf16*)alloc(128 * 128 * 2);
  bf16* PWsf = (bf16*)alloc(128 * 128 * 2);
  bf16* PWaf = (bf16*)alloc(128 * 128 * 2);
  bf16* PWps = (bf16*)alloc(256 * 128 * 2);
  bf16* PWss = (bf16*)alloc(256 * 128 * 2);
  bf16* PWas = (bf16*)alloc(256 * 128 * 2);
  bf16* PWo1 = (bf16*)alloc(512 * 128 * 2);
  bf16* nXsS = (bf16*)alloc((size_t)BTot * Dsz * 2);
  bf16* Sla = (bf16*)alloc((size_t)BTot * Dsz * 2);
  bf16* Slbp = (bf16*)alloc((size_t)BTot * Dsz * 2);
  bf16* Slbs = (bf16*)alloc((size_t)BTot * Dsz * 2);

  if (off > ws_size) {
    hipMemsetAsync(d_out, 0xFF, (size_t)out_size * 4, stream);
    return;
  }

  k_idx<<<Bsz, 256, 0, stream>>>(next_problem, next_skill, idx);
  k_pack<<<8, 256, 0, stream>>>(W_pf, PWpf, 128);
  k_pack<<<8, 256, 0, stream>>>(W_sf, PWsf, 128);
  k_pack<<<8, 256, 0, stream>>>(W_af, PWaf, 128);
  k_pack<<<16, 256, 0, stream>>>(W_ps, PWps, 256);
  k_pack<<<16, 256, 0, stream>>>(W_ss, PWss, 256);
  k_pack<<<16, 256, 0, stream>>>(W_as, PWas, 256);
  k_pack<<<32, 256, 0, stream>>>(W_o1, PWo1, 512);
  k_tge<<<200, 128, 0, stream>>>(time_embed, W_pf, b_pf, TGEp);
  k_tge<<<200, 128, 0, stream>>>(time_embed, W_sf, b_sf, TGEs);
  k_tge<<<1, 128, 0, stream>>>(time_embed + 128, W_af, b_af, cAF);
  k_embed<<<(BTot * 32 + 255) / 256, 256, 0, stream>>>(
      next_problem, next_skill, next_ans, pro_embed, skill_embed, akt_pro_diff,
      akt_pro_change, ans_embed, nXsS);

  MainParams mp;
  mp.ls_state = ls_state; mp.pro_state0 = pro_state0; mp.skill_state0 = skill_state0;
  mp.idx = idx;
  mp.nXsS = nXsS;
  mp.TGEp = TGEp; mp.TGEs = TGEs; mp.cAF = cAF;
  mp.PWpf = PWpf; mp.PWsf = PWsf; mp.PWaf = PWaf;
  mp.PWps = PWps; mp.PWss = PWss; mp.PWas = PWas;
  mp.b_ps = b_ps; mp.b_ss = b_ss; mp.b_as = b_as;
  mp.proSt = proSt; mp.skSt = skSt;
  mp.Sla = Sla; mp.Slbp = Slbp; mp.Slbs = Slbs;

  k_main<<<NBLK, 512, 0, stream>>>(mp);

  HeadParams hp;
  hp.Sla = Sla; hp.Slbp = Slbp; hp.Slbs = Slbs; hp.PWo1 = PWo1;
  hp.next_problem = next_problem; hp.next_skill = next_skill;
  hp.pro_embed = pro_embed; hp.skill_embed = skill_embed;
  hp.akt_pro_diff = akt_pro_diff; hp.akt_pro_change = akt_pro_change;
  hp.b_o1 = b_o1; hp.W_o2 = W_o2; hp.b_o2 = b_o2;
  hp.out = (float*)d_out;
  k_head<<<BTot / 32, 256, 0, stream>>>(hp);
}

// Round 9
// 715.659 us; speedup vs baseline: 1.7702x; 1.7702x over previous
//
#include <hip/hip_runtime.h>
#include <hip/hip_bf16.h>

typedef __bf16 bf16;
typedef bf16 bf16x8 __attribute__((ext_vector_type(8)));
typedef bf16 bf16x4 __attribute__((ext_vector_type(4)));
typedef float f32x4 __attribute__((ext_vector_type(4)));
typedef unsigned int u32;
typedef unsigned short u16;

#define Bsz 512
#define Ssz 199
#define Dsz 128
#define GR 16
#define NBLK (Bsz / GR)
#define BTot (Bsz * Ssz)

__device__ __forceinline__ float fsig(float x) {
  return __builtin_amdgcn_rcpf(1.f + __builtin_amdgcn_exp2f(x * -1.44269504f));
}
__device__ __forceinline__ float ftanh(float x) {
  return 1.f - 2.f * __builtin_amdgcn_rcpf(1.f + __builtin_amdgcn_exp2f(x * 2.88539008f));
}
__device__ __forceinline__ f32x4 mfma16(bf16x8 a, bf16x8 b, f32x4 c) {
  return __builtin_amdgcn_mfma_f32_16x16x32_bf16(a, b, c, 0, 0, 0);
}
__device__ __forceinline__ bf16x8 ldfrag(const bf16* PW, int KS, int nt, int ks, int lane) {
  return *(const bf16x8*)&PW[(size_t)((nt * KS + ks) * 64 + lane) * 8];
}
__device__ __forceinline__ void keep(bf16x8& v) {
  f32x4& f = reinterpret_cast<f32x4&>(v);
  asm volatile("" : "+v"(f));
}
// raw workgroup barrier: orders LDS only; global loads stay in flight across it
__device__ __forceinline__ void barL() {
  __builtin_amdgcn_sched_barrier(0);
  asm volatile("s_waitcnt lgkmcnt(0)" ::: "memory");
  __builtin_amdgcn_s_barrier();
  __builtin_amdgcn_sched_barrier(0);
}

// ---------------- K1: packed per-(b,t) index stream: lpt | lst<<8 ----------------
__global__ void k_idx(const int* __restrict__ np_, const int* __restrict__ ns_,
                      u32* __restrict__ idx) {
  __shared__ u16 tabP[20000];
  __shared__ u16 tabS[500];
  __shared__ u16 pb[Ssz], sb[Ssz];
  int b = blockIdx.x;
  for (int i = threadIdx.x; i < 20000; i += blockDim.x) tabP[i] = 0;
  for (int i = threadIdx.x; i < 500; i += blockDim.x) tabS[i] = 0;
  for (int i = threadIdx.x; i < Ssz; i += blockDim.x) {
    pb[i] = (u16)np_[b * Ssz + i];
    sb[i] = (u16)ns_[b * Ssz + i];
  }
  __syncthreads();
  if (threadIdx.x == 0) {
    for (int t = 0; t < Ssz; ++t) {
      int p = pb[t], s = sb[t];
      idx[b * Ssz + t] = (u32)tabP[p] | ((u32)tabS[s] << 8);
      tabP[p] = (u16)t;
      tabS[s] = (u16)t;
    }
  }
}

// ---------------- K2: pack weights into MFMA B-fragment layout ----------------
__global__ void k_pack(const float* __restrict__ W, bf16* __restrict__ dst, int K) {
  int g = blockIdx.x * blockDim.x + threadIdx.x;
  int KS = K / 32;
  int total = 8 * KS * 64;
  if (g >= total) return;
  int l = g & 63;
  int ks = (g >> 6) % KS;
  int nt = (g >> 6) / KS;
  int col = nt * 16 + (l & 15);
  int k0 = ks * 32 + (l >> 4) * 8;
  bf16x8 v;
  for (int j = 0; j < 8; ++j) v[j] = (bf16)W[(size_t)(k0 + j) * 128 + col];
  *(bf16x8*)&dst[(size_t)g * 8] = v;
}

// ---------------- K3: time-embedding projections (bias folded) ----------------
__global__ void k_tge(const float* __restrict__ TE, const float* __restrict__ W,
                      const float* __restrict__ bias, float* __restrict__ dst) {
  __shared__ float te[128];
  int d = blockIdx.x, n = threadIdx.x;
  te[n] = TE[d * 128 + n];
  __syncthreads();
  float acc = bias[n];
  for (int k = 0; k < 128; ++k) acc += te[k] * W[(size_t)(128 + k) * 128 + n];
  dst[d * 128 + n] = acc;
}

// ---------------- K4: nX stream, [t][B][128] bf16 ----------------
__global__ void k_embed(const int* __restrict__ np_, const int* __restrict__ ns_,
                        const int* __restrict__ na_,
                        const float* __restrict__ pe, const float* __restrict__ se,
                        const float* __restrict__ diff, const float* __restrict__ chg,
                        const float* __restrict__ ae, bf16* __restrict__ nXsS) {
  int g = blockIdx.x * 256 + threadIdx.x;
  int bt = g >> 5, cg = (g & 31) * 4;
  if (bt >= BTot) return;
  int b = bt / Ssz, t = bt - b * Ssz;
  int p = np_[bt], s = ns_[bt], a = na_[bt];
  float d = diff[p];
  f32x4 vp = *(const f32x4*)&pe[(size_t)p * 128 + cg];
  f32x4 vs = *(const f32x4*)&se[(size_t)s * 128 + cg];
  f32x4 vc = *(const f32x4*)&chg[(size_t)s * 128 + cg];
  f32x4 va = *(const f32x4*)&ae[(size_t)a * 128 + cg];
  bf16x4 ox;
  for (int j = 0; j < 4; ++j) ox[j] = (bf16)(vp[j] + vs[j] + d * vc[j] + va[j]);
  *(bf16x4*)&nXsS[((size_t)t * Bsz + b) * 128 + cg] = ox;
}

// ---------------- main recurrent kernel (R3 phase structure, deferred head) ----------------
struct MainParams {
  const float *ls_state, *pro_state0, *skill_state0;
  const u32 *idx;
  const bf16 *nXsS;
  const float *TGEp, *TGEs, *cAF;
  const bf16 *PWpf, *PWsf, *PWaf, *PWps, *PWss, *PWas;
  const float *b_ps, *b_ss, *b_as;
  bf16 *proSt, *skSt, *Sla, *Slbp, *Slbs;
};

__global__ void __launch_bounds__(512) k_main(MainParams P) {
  const int b0 = blockIdx.x * GR;
  const int tid = threadIdx.x;
  const int lane = tid & 63;
  const int wv = tid >> 6;        // wave owns output cols [wv*16, wv*16+16)
  const int r32 = tid >> 5;       // 0..15: gather row (c4 map)
  const int c4 = (tid & 31) * 4;  // gather col group
  const int arow = lane & 15, apos = (lane >> 4) * 8;
  const int rb = (lane >> 4) * 4;
  const int cA = wv * 16 + (lane & 15);

  __shared__ __align__(16) bf16 Ala[16][136], Albp[16][136], Albs[16][136], AnX[16][136];
  __shared__ __align__(16) bf16 STG0[16][132], STG1[16][132], STGa[16][132];
  __shared__ u32 idxL[GR * Ssz];

  // ---- register-resident weight slices (pinned) ----
  bf16x8 Wpf[4], Wsf[4], Waf[4], Wps[8], Wss[8], Was[8];
#pragma unroll
  for (int ks = 0; ks < 4; ++ks) {
    Wpf[ks] = ldfrag(P.PWpf, 4, wv, ks, lane);
    Wsf[ks] = ldfrag(P.PWsf, 4, wv, ks, lane);
    Waf[ks] = ldfrag(P.PWaf, 4, wv, ks, lane);
  }
#pragma unroll
  for (int ks = 0; ks < 8; ++ks) {
    Wps[ks] = ldfrag(P.PWps, 8, wv, ks, lane);
    Wss[ks] = ldfrag(P.PWss, 8, wv, ks, lane);
    Was[ks] = ldfrag(P.PWas, 8, wv, ks, lane);
  }
#pragma unroll
  for (int ks = 0; ks < 4; ++ks) {
    keep(Wpf[ks]);
    keep(Wsf[ks]);
    keep(Waf[ks]);
  }
#pragma unroll
  for (int ks = 0; ks < 8; ++ks) {
    keep(Wps[ks]);
    keep(Wss[ks]);
    keep(Was[ks]);
  }
  const float bpsv = P.b_ps[cA], bssv = P.b_ss[cA], basv = P.b_as[cA], cafv = P.cAF[cA];

  // ---- preload packed index stream (contiguous) ----
  for (int i = tid; i < GR * Ssz; i += 512) idxL[i] = P.idx[b0 * Ssz + i];
  __syncthreads();

  // ---- t = 0 state/gather init ----
  float gpc[4], gsc[4];
  {
    bf16x4 va, vp, vs;
    for (int j = 0; j < 4; ++j) {
      va[j] = (bf16)P.ls_state[c4 + j];
      vp[j] = (bf16)P.pro_state0[c4 + j];
      vs[j] = (bf16)P.skill_state0[c4 + j];
    }
    *(bf16x4*)&Ala[r32][c4] = va;
    *(bf16x4*)&Albp[r32][c4] = vp;
    *(bf16x4*)&Albs[r32][c4] = vs;
    *(bf16x4*)&AnX[r32][c4] = *(const bf16x4*)&P.nXsS[(size_t)(b0 + r32) * Dsz + c4];
#pragma unroll
    for (int r = 0; r < 4; ++r) {
      gpc[r] = P.TGEp[cA];  // t=0: lpt=lst=0 -> TGE row 0
      gsc[r] = P.TGEs[cA];
    }
  }
  __syncthreads();

  for (int t = 0; t < Ssz; ++t) {
    const bool pf = (t + 1 < Ssz);
    // ---- prefetch for t+1 (global loads; in flight across raw barriers) ----
    float gpn[4], gsn[4];
    bf16x4 pPro{}, pSk{}, pNxs{};
    u32 iwN = 0;
    if (pf) {
#pragma unroll
      for (int r = 0; r < 4; ++r) {
        u32 iw = idxL[(rb + r) * Ssz + t + 1];
        int lp = iw & 255, ls = (iw >> 8) & 255;
        gpn[r] = P.TGEp[(size_t)(t + 1 - lp) * Dsz + cA];
        gsn[r] = P.TGEs[(size_t)(t + 1 - ls) * Dsz + cA];
      }
      iwN = idxL[r32 * Ssz + t + 1];
      int lpN = iwN & 255, lsN = (iwN >> 8) & 255;
      if (lpN != t)
        pPro = *(const bf16x4*)&P.proSt[((size_t)(b0 + r32) * Ssz + lpN) * Dsz + c4];
      if (lsN != t)
        pSk = *(const bf16x4*)&P.skSt[((size_t)(b0 + r32) * Ssz + lsN) * Dsz + c4];
      pNxs = *(const bf16x4*)&P.nXsS[((size_t)(t + 1) * Bsz + (b0 + r32)) * Dsz + c4];
    }
    // ---- B: gate matmuls (K=128); gate bias pre-loaded into accumulators ----
    f32x4 dpf = {gpc[0], gpc[1], gpc[2], gpc[3]};
    f32x4 dsf = {gsc[0], gsc[1], gsc[2], gsc[3]};
    f32x4 daf = {cafv, cafv, cafv, cafv};
#pragma unroll
    for (int ks = 0; ks < 4; ++ks) {
      bf16x8 ap = *(const bf16x8*)&Albp[arow][ks * 32 + apos];
      bf16x8 av = *(const bf16x8*)&Albs[arow][ks * 32 + apos];
      bf16x8 aa = *(const bf16x8*)&Ala[arow][ks * 32 + apos];
      dpf = mfma16(ap, Wpf[ks], dpf);
      dsf = mfma16(av, Wsf[ks], dsf);
      daf = mfma16(aa, Waf[ks], daf);
    }
    barL();
    // ---- C: gate epilogue (in-place; gated values kept in f32 regs for E) ----
    float gP[4], gS[4], gA[4];
#pragma unroll
    for (int r = 0; r < 4; ++r) {
      int row = rb + r;
      float sp = (float)Albp[row][cA];
      float gv = sp * fsig(dpf[r]);
      gP[r] = gv;
      Albp[row][cA] = (bf16)gv;
      float ss = (float)Albs[row][cA];
      float gw = ss * fsig(dsf[r]);
      gS[r] = gw;
      Albs[row][cA] = (bf16)gw;
      float sa = (float)Ala[row][cA];
      float gx = sa * fsig(daf[r]);
      gA[r] = gx;
      Ala[row][cA] = (bf16)gx;
    }
    barL();
    // ---- D-top: head-input dumps (gated tiles are stable through D) ----
    {
      size_t db = ((size_t)(b0 + r32) * Ssz + t) * Dsz + c4;
      *(bf16x4*)&P.Sla[db] = *(const bf16x4*)&Ala[r32][c4];
      *(bf16x4*)&P.Slbp[db] = *(const bf16x4*)&Albp[r32][c4];
      *(bf16x4*)&P.Slbs[db] = *(const bf16x4*)&Albs[r32][c4];
    }
    // ---- D: update matmuls (K=256), weights in registers ----
    f32x4 uas{}, ups{}, uss{};
#pragma unroll
    for (int ks = 0; ks < 4; ++ks) {
      bf16x8 aa = *(const bf16x8*)&Ala[arow][ks * 32 + apos];
      bf16x8 ap = *(const bf16x8*)&Albp[arow][ks * 32 + apos];
      bf16x8 av = *(const bf16x8*)&Albs[arow][ks * 32 + apos];
      bf16x8 ax = *(const bf16x8*)&AnX[arow][ks * 32 + apos];
      uas = mfma16(aa, Was[ks], uas);
      uas = mfma16(ax, Was[ks + 4], uas);
      ups = mfma16(ap, Wps[ks], ups);
      ups = mfma16(ax, Wps[ks + 4], ups);
      uss = mfma16(av, Wss[ks], uss);
      uss = mfma16(ax, Wss[ks + 4], uss);
    }
    // ---- E: update epilogue (no barrier needed after D: acc deps are in-wave) ----
#pragma unroll
    for (int r = 0; r < 4; ++r) {
      int row = rb + r;
      STG0[row][cA] = (bf16)(gP[r] + ftanh(ups[r] + bpsv));
      STG1[row][cA] = (bf16)(gS[r] + ftanh(uss[r] + bssv));
      STGa[row][cA] = (bf16)(gA[r] + ftanh(uas[r] + basv));
    }
    barL();
    // ---- F: state writeback + install t+1 operands ----
    {
      size_t base = ((size_t)(b0 + r32) * Ssz + t) * Dsz + c4;
      bf16x4 npv = *(const bf16x4*)&STG0[r32][c4];
      bf16x4 nsv = *(const bf16x4*)&STG1[r32][c4];
      *(bf16x4*)&P.proSt[base] = npv;
      *(bf16x4*)&P.skSt[base] = nsv;
      if (pf) {
        int lpN = iwN & 255, lsN = (iwN >> 8) & 255;
        *(bf16x4*)&Ala[r32][c4] = *(const bf16x4*)&STGa[r32][c4];
        *(bf16x4*)&Albp[r32][c4] = (lpN == t) ? npv : pPro;
        *(bf16x4*)&Albs[r32][c4] = (lsN == t) ? nsv : pSk;
        *(bf16x4*)&AnX[r32][c4] = pNxs;
#pragma unroll
        for (int r = 0; r < 4; ++r) {
          gpc[r] = gpn[r];
          gsc[r] = gsn[r];
        }
      }
    }
    __syncthreads();  // full sync: drains this step's stores (visibility for t+2 gathers)
  }
}

// ---------------- deferred head: 32 rows/block ----------------
struct HeadParams {
  const bf16 *Sla, *Slbp, *Slbs, *PWo1;
  const int *next_problem, *next_skill;
  const float *pro_embed, *skill_embed, *akt_pro_diff, *akt_pro_change;
  const float *b_o1, *W_o2, *b_o2;
  float *out;
};

__global__ void k_head(HeadParams P) {
  const int bt0 = blockIdx.x * 32;
  const int tid = threadIdx.x, lane = tid & 63, wv = tid >> 6;
  const int r16 = tid >> 4, c8 = (tid & 15) * 8;
  const int arow = lane & 15, apos = (lane >> 4) * 8;
  const int rb = (lane >> 4) * 4;
  const int nt0 = wv, nt1 = wv + 4;
  const int cAh = nt0 * 16 + (lane & 15), cBh = nt1 * 16 + (lane & 15);
  __shared__ __align__(16) bf16 Af[32][520];
  __shared__ float Hh[32][132];
  __shared__ float Hpart[32][16];
  __shared__ float w2s[128];
  if (tid < 128) w2s[tid] = P.W_o2[tid];
  for (int half = 0; half < 2; ++half) {
    int row = half * 16 + r16;
    int bt = bt0 + row;
    *(bf16x8*)&Af[row][c8] = *(const bf16x8*)&P.Sla[(size_t)bt * 128 + c8];
    *(bf16x8*)&Af[row][128 + c8] = *(const bf16x8*)&P.Slbp[(size_t)bt * 128 + c8];
    *(bf16x8*)&Af[row][256 + c8] = *(const bf16x8*)&P.Slbs[(size_t)bt * 128 + c8];
    int np = P.next_problem[bt], ns = P.next_skill[bt];
    float diff = P.akt_pro_diff[np];
    f32x4 p0 = *(const f32x4*)&P.pro_embed[(size_t)np * 128 + c8];
    f32x4 p1 = *(const f32x4*)&P.pro_embed[(size_t)np * 128 + c8 + 4];
    f32x4 s0 = *(const f32x4*)&P.skill_embed[(size_t)ns * 128 + c8];
    f32x4 s1 = *(const f32x4*)&P.skill_embed[(size_t)ns * 128 + c8 + 4];
    f32x4 c0 = *(const f32x4*)&P.akt_pro_change[(size_t)ns * 128 + c8];
    f32x4 c1 = *(const f32x4*)&P.akt_pro_change[(size_t)ns * 128 + c8 + 4];
    bf16x8 vn;
    for (int j = 0; j < 4; ++j) {
      vn[j] = (bf16)(p0[j] + s0[j] + diff * c0[j]);
      vn[j + 4] = (bf16)(p1[j] + s1[j] + diff * c1[j]);
    }
    *(bf16x8*)&Af[row][384 + c8] = vn;
  }
  __syncthreads();
  f32x4 h0{}, h1{}, h2{}, h3{};
#pragma unroll
  for (int ks = 0; ks < 16; ++ks) {
    bf16x8 a0 = *(const bf16x8*)&Af[arow][ks * 32 + apos];
    bf16x8 a1 = *(const bf16x8*)&Af[16 + arow][ks * 32 + apos];
    bf16x8 bA = ldfrag(P.PWo1, 16, nt0, ks, lane);
    bf16x8 bB = ldfrag(P.PWo1, 16, nt1, ks, lane);
    h0 = mfma16(a0, bA, h0);
    h1 = mfma16(a0, bB, h1);
    h2 = mfma16(a1, bA, h2);
    h3 = mfma16(a1, bB, h3);
  }
  const float bo1A = P.b_o1[cAh], bo1B = P.b_o1[cBh];
  for (int r = 0; r < 4; ++r) {
    Hh[rb + r][cAh] = fmaxf(h0[r] + bo1A, 0.f);
    Hh[rb + r][cBh] = fmaxf(h1[r] + bo1B, 0.f);
    Hh[16 + rb + r][cAh] = fmaxf(h2[r] + bo1A, 0.f);
    Hh[16 + rb + r][cBh] = fmaxf(h3[r] + bo1B, 0.f);
  }
  __syncthreads();
  for (int half = 0; half < 2; ++half) {
    int row = half * 16 + (tid >> 4), cg = tid & 15;
    float s = 0.f;
#pragma unroll
    for (int j = 0; j < 8; ++j) s += Hh[row][cg * 8 + j] * w2s[cg * 8 + j];
    Hpart[row][cg] = s;
  }
  __syncthreads();
  if (tid < 32) {
    float s = 0.f;
#pragma unroll
    for (int k = 0; k < 16; ++k) s += Hpart[tid][k];
    P.out[bt0 + tid] = fsig(s + P.b_o2[0]);
  }
}

extern "C" void kernel_launch(void* const* d_in, const int* in_sizes, int n_in,
                              void* d_out, int out_size, void* d_ws, size_t ws_size,
                              hipStream_t stream) {
  const int* next_problem = (const int*)d_in[3];
  const int* next_skill = (const int*)d_in[4];
  const int* next_ans = (const int*)d_in[5];
  const float* pro_embed = (const float*)d_in[6];
  const float* skill_embed = (const float*)d_in[7];
  const float* ans_embed = (const float*)d_in[8];
  const float* time_embed = (const float*)d_in[9];
  const float* ls_state = (const float*)d_in[10];
  const float* pro_state0 = (const float*)d_in[11];
  const float* skill_state0 = (const float*)d_in[12];
  const float* akt_pro_diff = (const float*)d_in[13];
  const float* akt_pro_change = (const float*)d_in[14];
  const float* W_pf = (const float*)d_in[15];
  const float* b_pf = (const float*)d_in[16];
  const float* W_sf = (const float*)d_in[17];
  const float* b_sf = (const float*)d_in[18];
  const float* W_af = (const float*)d_in[19];
  const float* b_af = (const float*)d_in[20];
  const float* W_ps = (const float*)d_in[21];
  const float* b_ps = (const float*)d_in[22];
  const float* W_ss = (const float*)d_in[23];
  const float* b_ss = (const float*)d_in[24];
  const float* W_as = (const float*)d_in[25];
  const float* b_as = (const float*)d_in[26];
  const float* W_o1 = (const float*)d_in[27];
  const float* b_o1 = (const float*)d_in[28];
  const float* W_o2 = (const float*)d_in[29];
  const float* b_o2 = (const float*)d_in[30];

  char* ws = (char*)d_ws;
  size_t off = 0;
  auto alloc = [&](size_t bytes) -> void* {
    void* p = ws + off;
    off += bytes;
    off = (off + 255) & ~(size_t)255;
    return p;
  };
  bf16* proSt = (bf16*)alloc((size_t)Bsz * Ssz * Dsz * 2);
  bf16* skSt = (bf16*)alloc((size_t)Bsz * Ssz * Dsz * 2);
  u32* idx = (u32*)alloc((size_t)BTot * 4);
  float* TGEp = (float*)alloc(200 * 128 * 4);
  float* TGEs = (float*)alloc(200 * 128 * 4);
  float* cAF = (float*)alloc(128 * 4);
  bf16* PWpf = (bf16*)alloc(128 * 128 * 2);
  bf16* PWsf = (bf16*)alloc(128 * 128 * 2);
  bf16* PWaf = (bf16*)alloc(128 * 128 * 2);
  bf16* PWps = (bf16*)alloc(256 * 128 * 2);
  bf16* PWss = (bf16*)alloc(256 * 128 * 2);
  bf16* PWas = (bf16*)alloc(256 * 128 * 2);
  bf16* PWo1 = (bf16*)alloc(512 * 128 * 2);
  bf16* nXsS = (bf16*)alloc((size_t)BTot * Dsz * 2);
  bf16* Sla = (bf16*)alloc((size_t)BTot * Dsz * 2);
  bf16* Slbp = (bf16*)alloc((size_t)BTot * Dsz * 2);
  bf16* Slbs = (bf16*)alloc((size_t)BTot * Dsz * 2);

  if (off > ws_size) {
    hipMemsetAsync(d_out, 0xFF, (size_t)out_size * 4, stream);
    return;
  }

  k_idx<<<Bsz, 256, 0, stream>>>(next_problem, next_skill, idx);
  k_pack<<<8, 256, 0, stream>>>(W_pf, PWpf, 128);
  k_pack<<<8, 256, 0, stream>>>(W_sf, PWsf, 128);
  k_pack<<<8, 256, 0, stream>>>(W_af, PWaf, 128);
  k_pack<<<16, 256, 0, stream>>>(W_ps, PWps, 256);
  k_pack<<<16, 256, 0, stream>>>(W_ss, PWss, 256);
  k_pack<<<16, 256, 0, stream>>>(W_as, PWas, 256);
  k_pack<<<32, 256, 0, stream>>>(W_o1, PWo1, 512);
  k_tge<<<200, 128, 0, stream>>>(time_embed, W_pf, b_pf, TGEp);
  k_tge<<<200, 128, 0, stream>>>(time_embed, W_sf, b_sf, TGEs);
  k_tge<<<1, 128, 0, stream>>>(time_embed + 128, W_af, b_af, cAF);
  k_embed<<<(BTot * 32 + 255) / 256, 256, 0, stream>>>(
      next_problem, next_skill, next_ans, pro_embed, skill_embed, akt_pro_diff,
      akt_pro_change, ans_embed, nXsS);

  MainParams mp;
  mp.ls_state = ls_state; mp.pro_state0 = pro_state0; mp.skill_state0 = skill_state0;
  mp.idx = idx;
  mp.nXsS = nXsS;
  mp.TGEp = TGEp; mp.TGEs = TGEs; mp.cAF = cAF;
  mp.PWpf = PWpf; mp.PWsf = PWsf; mp.PWaf = PWaf;
  mp.PWps = PWps; mp.PWss = PWss; mp.PWas = PWas;
  mp.b_ps = b_ps; mp.b_ss = b_ss; mp.b_as = b_as;
  mp.proSt = proSt; mp.skSt = skSt;
  mp.Sla = Sla; mp.Slbp = Slbp; mp.Slbs = Slbs;

  k_main<<<NBLK, 512, 0, stream>>>(mp);

  HeadParams hp;
  hp.Sla = Sla; hp.Slbp = Slbp; hp.Slbs = Slbs; hp.PWo1 = PWo1;
  hp.next_problem = next_problem; hp.next_skill = next_skill;
  hp.pro_embed = pro_embed; hp.skill_embed = skill_embed;
  hp.akt_pro_diff = akt_pro_diff; hp.akt_pro_change = akt_pro_change;
  hp.b_o1 = b_o1; hp.W_o2 = W_o2; hp.b_o2 = b_o2;
  hp.out = (float*)d_out;
  k_head<<<BTot / 32, 256, 0, stream>>>(hp);
}